// Round 6
// baseline (228.682 us; speedup 1.0000x reference)
//
#include <hip/hip_runtime.h>
#include <hip/hip_cooperative_groups.h>
#include <math.h>

#define T_PTS 8192
#define NSOLVE 64
#define NLOG   16
#define NBLK   (NSOLVE + NLOG)
#define NTHR   512
#define NWAVE  (NTHR / 64)
#define NPT    128                // point-threads (4 tap-quarters share them)
#define PPT    9                  // ODD -> lane stride 9 words, coprime 32: conflict-free
#define WIN    (NPT * PPT)        // 1152-point window
#define CH     (T_PTS / NSOLVE)   // 128 owned points
#define HALO   ((WIN - CH) / 2)   // 512
#define BS     144                // 12 groups of 12 taps; 3 per quarter
#define NGQ    3                  // tap-groups per quarter
#define ITERS  28                 // measured absmax 32 << 89 at 28 (R3-R5)
#define GL     144                // left guard: group 11 reaches cb-144
#define LDSN   (GL + WIN + 144)   // 1440; max read = GL+1143+152 = 1439
#define BF     256                // logdet symbol band (validated R1-R5)
#define KCORR  768                // Szego modes (validated R1-R5)
#define KPERB  (KCORR / NLOG)     // 48

// ws: [0..23] acc{logdet0,szego,quad} f64 | 32 bar | 36 done | 64.. lg float[8192]

__device__ inline double blockReduceSum(double v, double* lds) {
#pragma unroll
    for (int o = 32; o > 0; o >>= 1) v += __shfl_down(v, o, 64);
    const int lane = threadIdx.x & 63, wid = threadIdx.x >> 6;
    __syncthreads();
    if (lane == 0) lds[wid] = v;
    __syncthreads();
    double r = 0.0;
    if (threadIdx.x == 0) {
#pragma unroll
        for (int i = 0; i < NWAVE; ++i) r += lds[i];
    }
    return r;   // valid on thread 0 only
}

struct SolverSh {
    float dbuf[2][LDSN];          // double-buffered d vector (+zero guards)
    float pac[3][PPT][NPT];       // partials from quarters 1..3
    float wv[BS];                 // wv[d-1] = w_d
    float lmax;
};
struct LogdetSh {
    float lgl[T_PTS];
    float wlg[BF + 1];
};
union ShMem { SolverSh s; LogdetSh l; };

__global__ __launch_bounds__(NTHR, 2) void gp_mll_kernel(
    const float* __restrict__ y, const float* __restrict__ s2p,
    const float* __restrict__ ellp, const float* __restrict__ varp,
    float* __restrict__ out, unsigned char* __restrict__ wsb)
{
    __shared__ __align__(16) ShMem sh;
    __shared__ double redd[NWAVE];

    double* acc  = (double*)wsb;
    int*    bar  = (int*)(wsb + 32);
    int*    done = (int*)(wsb + 36);
    float*  lg   = (float*)(wsb + 64);

    const int tid = threadIdx.x, bid = blockIdx.x;
    const float sig2 = s2p[0], ell = ellp[0], var = varp[0];
    const float inv2l2 = 1.0f / (2.0f * ell * ell);

    if (bid < NSOLVE) {
        // ====== windowed Chebyshev solver: odd-stride layout, tap-server quarters ======
        SolverSh& S = sh.s;
        for (int d = tid; d < BS; d += NTHR)
            S.wv[d] = var * expf(-(float)((d + 1) * (d + 1)) * inv2l2);
        for (int i = tid; i < LDSN; i += NTHR) { S.dbuf[0][i] = 0.f; S.dbuf[1][i] = 0.f; }
        __syncthreads();
        if (tid == 0) {
            float s = 0.f;
            for (int d = 0; d < BS; ++d) s += S.wv[d];
            S.lmax = sig2 + var + 2.f * s;        // symbol sup >= lambda_max
        }
        __syncthreads();
        const float lmax = S.lmax, lmin = sig2;   // K PSD => lmin >= sigma^2
        const float theta = 0.5f * (lmax + lmin), delta = 0.5f * (lmax - lmin);
        const float s1 = theta / delta;
        const float invtheta = 1.f / theta;
        const float a0 = sig2 + var;

        const int pt = tid & (NPT - 1);
        const int q  = tid >> 7;                  // 0..3, wave-uniform (2 waves each)
        const int i0 = pt * PPT;
        const int g0 = bid * CH - HALO + i0;
        const int cb = GL + i0;                   // lane stride 9 words

        // weights for my 36 taps -> registers (one-time LDS broadcasts)
        float wreg[NGQ][12];
#pragma unroll
        for (int j = 0; j < NGQ; ++j)
#pragma unroll
            for (int k = 0; k < 12; ++k)
                wreg[j][k] = S.wv[12 * (q * NGQ + j) + k];

        float rr[PPT], xx[PPT], yv[PPT], mk[PPT];
        if (q == 0) {
#pragma unroll
            for (int p = 0; p < PPT; ++p) {
                const int g = g0 + p;
                const bool in = (g >= 0) && (g < T_PTS);
                yv[p] = in ? y[g] : 0.f;
                mk[p] = in ? 1.f : 0.f;
                rr[p] = yv[p]; xx[p] = 0.f;
                S.dbuf[0][cb + p] = yv[p] * invtheta;
            }
        } else {
#pragma unroll
            for (int p = 0; p < PPT; ++p) { yv[p]=0.f; mk[p]=0.f; rr[p]=0.f; xx[p]=0.f; }
        }
        float rho = 1.f / s1;
        __syncthreads();

        for (int it = 0; it < ITERS; ++it) {
            const float* src = S.dbuf[it & 1];
            float*       dst = S.dbuf[(it + 1) & 1];

            float dk[PPT], ac[PPT];
            if (q == 0) {
#pragma unroll
                for (int p = 0; p < PPT; ++p) { dk[p] = src[cb + p]; ac[p] = a0 * dk[p]; }
            } else {
#pragma unroll
                for (int p = 0; p < PPT; ++p) { dk[p] = 0.f; ac[p] = 0.f; }
            }

#pragma unroll
            for (int j = 0; j < NGQ; ++j) {
                const int g = q * NGQ + j;                 // 0..11 across quarters
                const int lb = cb - 12 * g - 12;           // la[h] = src[lb+h], h=0..19
                const int rb = cb + 12 * g + 1;            // ra[h] = src[rb+h]
                float la[20], ra[20];
#pragma unroll
                for (int h = 0; h < 20; ++h) la[h] = src[lb + h];   // stride 9: free
#pragma unroll
                for (int h = 0; h < 20; ++h) ra[h] = src[rb + h];
                // tap d = 12g+1+k: src[cb+p-d] = la[11-k+p], src[cb+p+d] = ra[k+p]
#pragma unroll
                for (int k = 0; k < 12; ++k)
#pragma unroll
                    for (int p = 0; p < PPT; ++p)
                        ac[p] = fmaf(wreg[j][k], la[11 - k + p] + ra[k + p], ac[p]);
            }

            if (q > 0) {
#pragma unroll
                for (int p = 0; p < PPT; ++p) S.pac[q - 1][p][pt] = ac[p];   // stride 1: free
            }
            __syncthreads();            // partials visible

            const float rho1 = 1.f / (2.f * s1 - rho);
            const float c1 = rho1 * rho, c2 = 2.f * rho1 / delta;
            rho = rho1;
            if (q == 0) {
#pragma unroll
                for (int p = 0; p < PPT; ++p) {
                    const float act = ac[p] + S.pac[0][p][pt] + S.pac[1][p][pt]
                                            + S.pac[2][p][pt];
                    xx[p] += dk[p];
                    rr[p] -= act;
                    dst[cb + p] = mk[p] * (c1 * dk[p] + c2 * rr[p]);   // ghosts stay 0
                }
            }
            __syncthreads();            // dst visible; pac reusable next iter
        }

        // quad over OWNED points (quarter 0 only; others contribute 0)
        double qd = 0.0;
        if (q == 0) {
#pragma unroll
            for (int p = 0; p < PPT; ++p) {
                const int iw = i0 + p;
                if (iw >= HALO && iw < HALO + CH)
                    qd += (double)yv[p] * (double)xx[p];
            }
        }
        const double qs = blockReduceSum(qd, redd);
        if (tid == 0) atomicAdd(&acc[2], qs);
    } else {
        // ================= logdet: circulant + strong Szego =================
        LogdetSh& L = sh.l;
        const int lbk = bid - NSOLVE;
        for (int d = tid; d <= BF; d += NTHR)
            L.wlg[d] = var * expf(-(float)(d * d) * inv2l2);
        __syncthreads();
        const float ang0 = 7.66990393942820614859e-4f;   // 2*pi/8192
        const int j = lbk * NTHR + tid;                  // my frequency index
        float fj = sig2 + var;
        for (int d = 1; d <= BF; ++d) {
            int m = (j * d) & (T_PTS - 1);               // exact int phase
            if (m >= T_PTS / 2) m -= T_PTS;
            fj += 2.f * L.wlg[d] * cosf(ang0 * (float)m);
        }
        const float lgj = logf(fj);
        lg[j] = lgj;                                     // publish to ws
        const double ls = blockReduceSum((double)lgj, redd);
        if (tid == 0) atomicAdd(&acc[0], ls);            // circulant term
        __threadfence();                                 // release my lg store
        __syncthreads();
        if (tid == 0) {                                  // sub-barrier, NLOG blocks
            atomicAdd(bar, 1);
            while (__hip_atomic_load(bar, __ATOMIC_ACQUIRE, __HIP_MEMORY_SCOPE_AGENT) < NLOG)
                __builtin_amdgcn_s_sleep(8);
        }
        __syncthreads();
        for (int i = tid; i < T_PTS; i += NTHR) L.lgl[i] = lg[i];   // stage to LDS
        __syncthreads();
        double corr = 0.0;
        for (int t = 0; t < KPERB; ++t) {
            const int k = lbk * KPERB + t + 1;
            double p = 0.0;
            for (int jj = tid; jj < T_PTS; jj += NTHR) {
                int m = (jj * k) & (T_PTS - 1);
                if (m >= T_PTS / 2) m -= T_PTS;
                p += (double)(L.lgl[jj] * __cosf(ang0 * (float)m));
            }
            double ckv = blockReduceSum(p, redd);
            if (tid == 0) {
                ckv *= (1.0 / (double)T_PTS);
                corr += (double)k * ckv * ckv;
            }
        }
        if (tid == 0) atomicAdd(&acc[1], corr);
    }

    // ================= last-block combine =================
    __syncthreads();
    if (tid == 0) {
        __threadfence();
        const int old = atomicAdd(done, 1);
        if (old == NBLK - 1) {
            __threadfence();
            const double l0 = __hip_atomic_load(&acc[0], __ATOMIC_RELAXED, __HIP_MEMORY_SCOPE_AGENT);
            const double l1 = __hip_atomic_load(&acc[1], __ATOMIC_RELAXED, __HIP_MEMORY_SCOPE_AGENT);
            const double qq = __hip_atomic_load(&acc[2], __ATOMIC_RELAXED, __HIP_MEMORY_SCOPE_AGENT);
            out[0] = (float)(-0.5 * qq - 0.5 * (l0 + l1));
        }
    }
}

extern "C" void kernel_launch(void* const* d_in, const int* in_sizes, int n_in,
                              void* d_out, int out_size, void* d_ws, size_t ws_size,
                              hipStream_t stream) {
    const float* y    = (const float*)d_in[0];
    const float* sig2 = (const float*)d_in[1];
    const float* ell  = (const float*)d_in[2];
    const float* var  = (const float*)d_in[3];
    float* out = (float*)d_out;
    unsigned char* ws = (unsigned char*)d_ws;

    hipMemsetAsync(d_ws, 0, 64, stream);   // acc[3] + bar + done only

    void* args[] = { (void*)&y, (void*)&sig2, (void*)&ell, (void*)&var,
                     (void*)&out, (void*)&ws };
    hipLaunchCooperativeKernel((void*)gp_mll_kernel, dim3(NBLK), dim3(NTHR),
                               args, 0, stream);
}

// Round 7
// 195.479 us; speedup vs baseline: 1.1699x; 1.1699x over previous
//
#include <hip/hip_runtime.h>
#include <hip/hip_cooperative_groups.h>
#include <math.h>

#define T_PTS 8192
#define NSOLVE 64
#define NLOG   16
#define NBLK   (NSOLVE + NLOG)
#define NTHR   512
#define NWAVE  (NTHR / 64)
#define NPT    128                // point-threads (4 tap-quarters share them)
#define PPT    9                  // ODD -> lane stride 9 words, coprime 32: conflict-free (R6: 0 conflicts)
#define WIN    (NPT * PPT)        // 1152-point window
#define CH     (T_PTS / NSOLVE)   // 128 owned points
#define HALO   ((WIN - CH) / 2)   // 512
#define BS     144                // 12 groups of 12 taps; 3 per quarter
#define NGQ    3                  // tap-groups per quarter
#define ITERS  28                 // measured absmax 32 << 89 (R3-R6)
#define GL     144                // left guard: group 11 reaches cb-144
#define LDSN   (GL + WIN + 144)   // 1440; max read = 1287+152 = 1439
#define BF     256                // logdet symbol band (validated R1-R6)
#define KCORR  768                // Szego modes (validated R1-R6)
#define KPERB  (KCORR / NLOG)     // 48

// ws: [0..23] acc{logdet0,szego,quad} f64 | 32 bar | 36 done | 64.. lg float[8192]

__device__ inline double blockReduceSum(double v, double* lds) {
#pragma unroll
    for (int o = 32; o > 0; o >>= 1) v += __shfl_down(v, o, 64);
    const int lane = threadIdx.x & 63, wid = threadIdx.x >> 6;
    __syncthreads();
    if (lane == 0) lds[wid] = v;
    __syncthreads();
    double r = 0.0;
    if (threadIdx.x == 0) {
#pragma unroll
        for (int i = 0; i < NWAVE; ++i) r += lds[i];
    }
    return r;   // valid on thread 0 only
}

struct SolverSh {
    float dbuf[2][LDSN];          // double-buffered d vector (+zero guards)
    float pac[3][PPT][NPT];       // partials from quarters 1..3
    float wv[BS];                 // wv[d-1] = w_d
    float lmax;
};
struct LogdetSh {
    float lgl[T_PTS];
    float wlg[BF + 1];
};
union ShMem { SolverSh s; LogdetSh l; };

__global__ __launch_bounds__(NTHR, 1) void gp_mll_kernel(
    const float* __restrict__ y, const float* __restrict__ s2p,
    const float* __restrict__ ellp, const float* __restrict__ varp,
    float* __restrict__ out, unsigned char* __restrict__ wsb)
{
    __shared__ __align__(16) ShMem sh;
    __shared__ double redd[NWAVE];

    double* acc  = (double*)wsb;
    int*    bar  = (int*)(wsb + 32);
    int*    done = (int*)(wsb + 36);
    float*  lg   = (float*)(wsb + 64);

    const int tid = threadIdx.x, bid = blockIdx.x;
    const float sig2 = s2p[0], ell = ellp[0], var = varp[0];
    const float inv2l2 = 1.0f / (2.0f * ell * ell);

    if (bid < NSOLVE) {
        // ====== windowed Chebyshev solver: odd-stride layout, tap-server quarters ======
        SolverSh& S = sh.s;
        for (int d = tid; d < BS; d += NTHR)
            S.wv[d] = var * expf(-(float)((d + 1) * (d + 1)) * inv2l2);
        for (int i = tid; i < LDSN; i += NTHR) { S.dbuf[0][i] = 0.f; S.dbuf[1][i] = 0.f; }
        __syncthreads();
        if (tid == 0) {
            float s = 0.f;
            for (int d = 0; d < BS; ++d) s += S.wv[d];
            S.lmax = sig2 + var + 2.f * s;        // symbol sup >= lambda_max
        }
        __syncthreads();
        const float lmax = S.lmax, lmin = sig2;   // K PSD => lmin >= sigma^2
        const float theta = 0.5f * (lmax + lmin), delta = 0.5f * (lmax - lmin);
        const float s1 = theta / delta;
        const float invtheta = 1.f / theta;
        const float a0 = sig2 + var;

        const int pt = tid & (NPT - 1);
        const int q  = tid >> 7;                  // 0..3, wave-uniform (2 waves each)
        const int i0 = pt * PPT;
        const int g0 = bid * CH - HALO + i0;
        const int cb = GL + i0;                   // lane stride 9 words: conflict-free

        float rr[PPT], xx[PPT];
        if (q == 0) {
#pragma unroll
            for (int p = 0; p < PPT; ++p) {
                const bool in = (unsigned)(g0 + p) < (unsigned)T_PTS;
                const float yv = in ? y[g0 + p] : 0.f;
                rr[p] = yv; xx[p] = 0.f;
                S.dbuf[0][cb + p] = yv * invtheta;
            }
        } else {
#pragma unroll
            for (int p = 0; p < PPT; ++p) { rr[p] = 0.f; xx[p] = 0.f; }
        }
        float rho = 1.f / s1;
        __syncthreads();

        for (int it = 0; it < ITERS; ++it) {
            const float* src = S.dbuf[it & 1];
            float*       dst = S.dbuf[(it + 1) & 1];

            float dk[PPT], ac[PPT];
            if (q == 0) {
#pragma unroll
                for (int p = 0; p < PPT; ++p) { dk[p] = src[cb + p]; ac[p] = a0 * dk[p]; }
            } else {
#pragma unroll
                for (int p = 0; p < PPT; ++p) { dk[p] = 0.f; ac[p] = 0.f; }
            }

#pragma unroll
            for (int j = 0; j < NGQ; ++j) {
                const int g = q * NGQ + j;                 // 0..11 across quarters
                const int lb = cb - 12 * g - 12;           // la[h] = src[lb+h]
                const int rb = cb + 12 * g + 1;            // ra[h] = src[rb+h]
                float wg[12];
#pragma unroll
                for (int k = 0; k < 12; ++k) wg[k] = S.wv[12 * g + k];   // broadcast: free
                float la[20], ra[20];
#pragma unroll
                for (int h = 0; h < 20; ++h) la[h] = src[lb + h];   // stride 9: conflict-free
#pragma unroll
                for (int h = 0; h < 20; ++h) ra[h] = src[rb + h];
                // tap d = 12g+1+k: src[cb+p-d] = la[11-k+p], src[cb+p+d] = ra[k+p]
#pragma unroll
                for (int k = 0; k < 12; ++k)
#pragma unroll
                    for (int p = 0; p < PPT; ++p)
                        ac[p] = fmaf(wg[k], la[11 - k + p] + ra[k + p], ac[p]);
            }

            if (q > 0) {
#pragma unroll
                for (int p = 0; p < PPT; ++p) S.pac[q - 1][p][pt] = ac[p];   // stride 1: free
            }
            __syncthreads();            // partials visible

            const float rho1 = 1.f / (2.f * s1 - rho);
            const float c1 = rho1 * rho, c2 = 2.f * rho1 / delta;
            rho = rho1;
            if (q == 0) {
#pragma unroll
                for (int p = 0; p < PPT; ++p) {
                    const float act = ac[p] + S.pac[0][p][pt] + S.pac[1][p][pt]
                                            + S.pac[2][p][pt];
                    xx[p] += dk[p];
                    rr[p] -= act;
                    const bool in = (unsigned)(g0 + p) < (unsigned)T_PTS;
                    dst[cb + p] = in ? (c1 * dk[p] + c2 * rr[p]) : 0.f;   // ghosts stay 0
                }
            }
            __syncthreads();            // dst visible; pac reusable next iter
        }

        // quad over OWNED points (quarter 0 only; reload y to avoid persistent regs)
        double qd = 0.0;
        if (q == 0) {
#pragma unroll
            for (int p = 0; p < PPT; ++p) {
                const int iw = i0 + p;
                if (iw >= HALO && iw < HALO + CH)
                    qd += (double)y[g0 + p] * (double)xx[p];
            }
        }
        const double qs = blockReduceSum(qd, redd);
        if (tid == 0) atomicAdd(&acc[2], qs);
    } else {
        // ================= logdet: circulant + strong Szego =================
        LogdetSh& L = sh.l;
        const int lbk = bid - NSOLVE;
        for (int d = tid; d <= BF; d += NTHR)
            L.wlg[d] = var * expf(-(float)(d * d) * inv2l2);
        __syncthreads();
        const float ang0 = 7.66990393942820614859e-4f;   // 2*pi/8192
        const int j = lbk * NTHR + tid;                  // my frequency index
        float fj = sig2 + var;
        for (int d = 1; d <= BF; ++d) {
            int m = (j * d) & (T_PTS - 1);               // exact int phase
            if (m >= T_PTS / 2) m -= T_PTS;
            fj += 2.f * L.wlg[d] * cosf(ang0 * (float)m);
        }
        const float lgj = logf(fj);
        lg[j] = lgj;                                     // publish to ws
        const double ls = blockReduceSum((double)lgj, redd);
        if (tid == 0) atomicAdd(&acc[0], ls);            // circulant term
        __threadfence();                                 // release my lg store
        __syncthreads();
        if (tid == 0) {                                  // sub-barrier, NLOG blocks
            atomicAdd(bar, 1);
            while (__hip_atomic_load(bar, __ATOMIC_ACQUIRE, __HIP_MEMORY_SCOPE_AGENT) < NLOG)
                __builtin_amdgcn_s_sleep(8);
        }
        __syncthreads();
        for (int i = tid; i < T_PTS; i += NTHR) L.lgl[i] = lg[i];   // stage to LDS
        __syncthreads();
        double corr = 0.0;
        for (int t = 0; t < KPERB; ++t) {
            const int k = lbk * KPERB + t + 1;
            double p = 0.0;
            for (int jj = tid; jj < T_PTS; jj += NTHR) {
                int m = (jj * k) & (T_PTS - 1);
                if (m >= T_PTS / 2) m -= T_PTS;
                p += (double)(L.lgl[jj] * __cosf(ang0 * (float)m));
            }
            double ckv = blockReduceSum(p, redd);
            if (tid == 0) {
                ckv *= (1.0 / (double)T_PTS);
                corr += (double)k * ckv * ckv;
            }
        }
        if (tid == 0) atomicAdd(&acc[1], corr);
    }

    // ================= last-block combine =================
    __syncthreads();
    if (tid == 0) {
        __threadfence();
        const int old = atomicAdd(done, 1);
        if (old == NBLK - 1) {
            __threadfence();
            const double l0 = __hip_atomic_load(&acc[0], __ATOMIC_RELAXED, __HIP_MEMORY_SCOPE_AGENT);
            const double l1 = __hip_atomic_load(&acc[1], __ATOMIC_RELAXED, __HIP_MEMORY_SCOPE_AGENT);
            const double qq = __hip_atomic_load(&acc[2], __ATOMIC_RELAXED, __HIP_MEMORY_SCOPE_AGENT);
            out[0] = (float)(-0.5 * qq - 0.5 * (l0 + l1));
        }
    }
}

extern "C" void kernel_launch(void* const* d_in, const int* in_sizes, int n_in,
                              void* d_out, int out_size, void* d_ws, size_t ws_size,
                              hipStream_t stream) {
    const float* y    = (const float*)d_in[0];
    const float* sig2 = (const float*)d_in[1];
    const float* ell  = (const float*)d_in[2];
    const float* var  = (const float*)d_in[3];
    float* out = (float*)d_out;
    unsigned char* ws = (unsigned char*)d_ws;

    hipMemsetAsync(d_ws, 0, 64, stream);   // acc[3] + bar + done only

    void* args[] = { (void*)&y, (void*)&sig2, (void*)&ell, (void*)&var,
                     (void*)&out, (void*)&ws };
    hipLaunchCooperativeKernel((void*)gp_mll_kernel, dim3(NBLK), dim3(NTHR),
                               args, 0, stream);
}

// Round 8
// 187.372 us; speedup vs baseline: 1.2205x; 1.0433x over previous
//
#include <hip/hip_runtime.h>
#include <hip/hip_cooperative_groups.h>
#include <math.h>

#define T_PTS 8192
#define NSOLVE 64
#define NLOG   16
#define NBLK   (NSOLVE + NLOG)
#define NTHR   512
#define NWAVE  (NTHR / 64)
#define NPT    128                // point-threads (4 tap-quarters share them)
#define PPT    10                 // lane stride 10 words -> b64 hits every bank exactly 4x: conflict-free
#define WIN    (NPT * PPT)        // 1280-point window
#define CH     (T_PTS / NSOLVE)   // 128 owned points
#define HALO   ((WIN - CH) / 2)   // 576
#define BS     144                // 12 groups of 12 taps; 3 per quarter
#define NGQ    3                  // tap-groups per quarter
#define ITERS  28                 // measured absmax 32 << 89 (R3-R7)
#define GL     144                // left guard (even): group 11 reaches cb-144
#define LDSN   1580               // max read idx = 144+1270+132+21 = 1567
#define BF     256                // logdet symbol band (validated R1-R7)
#define KCORR  768                // Szego modes (validated R1-R7)
#define KPERB  (KCORR / NLOG)     // 48

// ws: [0..23] acc{logdet0,szego,quad} f64 | 32 bar | 36 done | 64.. lg float[8192]

__device__ inline double blockReduceSum(double v, double* lds) {
#pragma unroll
    for (int o = 32; o > 0; o >>= 1) v += __shfl_down(v, o, 64);
    const int lane = threadIdx.x & 63, wid = threadIdx.x >> 6;
    __syncthreads();
    if (lane == 0) lds[wid] = v;
    __syncthreads();
    double r = 0.0;
    if (threadIdx.x == 0) {
#pragma unroll
        for (int i = 0; i < NWAVE; ++i) r += lds[i];
    }
    return r;   // valid on thread 0 only
}

struct SolverSh {
    float dbuf[2][LDSN];          // double-buffered d vector (+zero guards)
    float pac[3][PPT][NPT];       // partials from quarters 1..3 (stride-1 planes)
    float wv[BS];                 // wv[d-1] = w_d
    float lmax;
};
struct LogdetSh {
    float lgl[T_PTS];
    float wlg[BF + 1];
};
union ShMem { SolverSh s; LogdetSh l; };

__global__ __launch_bounds__(NTHR, 1) void gp_mll_kernel(
    const float* __restrict__ y, const float* __restrict__ s2p,
    const float* __restrict__ ellp, const float* __restrict__ varp,
    float* __restrict__ out, unsigned char* __restrict__ wsb)
{
    __shared__ __align__(16) ShMem sh;
    __shared__ double redd[NWAVE];

    double* acc  = (double*)wsb;
    int*    bar  = (int*)(wsb + 32);
    int*    done = (int*)(wsb + 36);
    float*  lg   = (float*)(wsb + 64);

    const int tid = threadIdx.x, bid = blockIdx.x;
    const float sig2 = s2p[0], ell = ellp[0], var = varp[0];
    const float inv2l2 = 1.0f / (2.0f * ell * ell);

    if (bid < NSOLVE) {
        // ====== windowed Chebyshev solver: stride-10 b64 layout, tap-server quarters ======
        SolverSh& S = sh.s;
        for (int d = tid; d < BS; d += NTHR)
            S.wv[d] = var * expf(-(float)((d + 1) * (d + 1)) * inv2l2);
        for (int i = tid; i < LDSN; i += NTHR) { S.dbuf[0][i] = 0.f; S.dbuf[1][i] = 0.f; }
        __syncthreads();
        if (tid == 0) {
            float s = 0.f;
            for (int d = 0; d < BS; ++d) s += S.wv[d];
            S.lmax = sig2 + var + 2.f * s;        // symbol sup >= lambda_max
        }
        __syncthreads();
        const float lmax = S.lmax, lmin = sig2;   // K PSD => lmin >= sigma^2
        const float theta = 0.5f * (lmax + lmin), delta = 0.5f * (lmax - lmin);
        const float s1 = theta / delta;
        const float invtheta = 1.f / theta;
        const float a0 = sig2 + var;

        const int pt = tid & (NPT - 1);
        const int q  = tid >> 7;                  // 0..3, wave-uniform (2 waves each)
        const int i0 = pt * PPT;
        const int g0 = bid * CH - HALO + i0;
        const int cb = GL + i0;                   // even; lane stride 10 words

        float rr[PPT], xx[PPT];
        if (q == 0) {
#pragma unroll
            for (int p = 0; p < PPT; ++p) {
                const bool in = (unsigned)(g0 + p) < (unsigned)T_PTS;
                const float yv = in ? y[g0 + p] : 0.f;
                rr[p] = yv; xx[p] = 0.f;
                S.dbuf[0][cb + p] = yv * invtheta;
            }
        } else {
#pragma unroll
            for (int p = 0; p < PPT; ++p) { rr[p] = 0.f; xx[p] = 0.f; }
        }
        float rho = 1.f / s1;
        __syncthreads();

        const float2* wv2 = (const float2*)S.wv;
        for (int it = 0; it < ITERS; ++it) {
            const float* src = S.dbuf[it & 1];
            float*       dst = S.dbuf[(it + 1) & 1];
            const float2* s2 = (const float2*)src;

            float dk[PPT], ac[PPT];
            if (q == 0) {
#pragma unroll
                for (int h = 0; h < PPT / 2; ++h) {
                    float2 t = s2[(cb >> 1) + h];
                    dk[2*h] = t.x; dk[2*h+1] = t.y;
                }
#pragma unroll
                for (int p = 0; p < PPT; ++p) ac[p] = a0 * dk[p];
            } else {
#pragma unroll
                for (int p = 0; p < PPT; ++p) { dk[p] = 0.f; ac[p] = 0.f; }
            }

#pragma unroll
            for (int j = 0; j < NGQ; ++j) {
                const int g = q * NGQ + j;                 // 0..11 across quarters
                const int lb2 = (cb - 12 * g - 12) >> 1;   // even bases: exact float2
                const int rb2 = (cb + 12 * g) >> 1;
                float la[22], ra[22], wg[12];
#pragma unroll
                for (int h = 0; h < 11; ++h) {
                    float2 t = s2[lb2 + h];
                    la[2*h] = t.x; la[2*h+1] = t.y;        // la[h]=src[cb-12g-12+h]
                }
#pragma unroll
                for (int h = 0; h < 11; ++h) {
                    float2 t = s2[rb2 + h];
                    ra[2*h] = t.x; ra[2*h+1] = t.y;        // ra[h]=src[cb+12g+h]
                }
#pragma unroll
                for (int h = 0; h < 6; ++h) {
                    float2 t = wv2[6 * g + h];             // broadcast
                    wg[2*h] = t.x; wg[2*h+1] = t.y;
                }
                // tap d = 12g+1+k: src[cb+p-d] = la[p+11-k], src[cb+p+d] = ra[p+1+k]
#pragma unroll
                for (int k = 0; k < 12; ++k)
#pragma unroll
                    for (int p = 0; p < PPT; ++p)
                        ac[p] = fmaf(wg[k], la[p + 11 - k] + ra[p + 1 + k], ac[p]);
            }

            if (q > 0) {
#pragma unroll
                for (int p = 0; p < PPT; ++p) S.pac[q - 1][p][pt] = ac[p];   // stride-1: free
            }
            __syncthreads();            // partials visible

            const float rho1 = 1.f / (2.f * s1 - rho);
            const float c1 = rho1 * rho, c2 = 2.f * rho1 / delta;
            rho = rho1;
            if (q == 0) {
                float dn[PPT];
#pragma unroll
                for (int p = 0; p < PPT; ++p) {
                    const float act = ac[p] + S.pac[0][p][pt] + S.pac[1][p][pt]
                                            + S.pac[2][p][pt];
                    xx[p] += dk[p];
                    rr[p] -= act;
                    const bool in = (unsigned)(g0 + p) < (unsigned)T_PTS;
                    dn[p] = in ? (c1 * dk[p] + c2 * rr[p]) : 0.f;   // ghosts stay 0
                }
                float2* d2 = (float2*)dst;
#pragma unroll
                for (int h = 0; h < PPT / 2; ++h)
                    d2[(cb >> 1) + h] = make_float2(dn[2*h], dn[2*h+1]);
            }
            __syncthreads();            // dst visible; pac reusable next iter
        }

        // quad over OWNED points (quarter 0 only; reload y to avoid persistent regs)
        double qd = 0.0;
        if (q == 0) {
#pragma unroll
            for (int p = 0; p < PPT; ++p) {
                const int iw = i0 + p;
                if (iw >= HALO && iw < HALO + CH)
                    qd += (double)y[g0 + p] * (double)xx[p];
            }
        }
        const double qs = blockReduceSum(qd, redd);
        if (tid == 0) atomicAdd(&acc[2], qs);
    } else {
        // ================= logdet: circulant + strong Szego =================
        LogdetSh& L = sh.l;
        const int lbk = bid - NSOLVE;
        for (int d = tid; d <= BF; d += NTHR)
            L.wlg[d] = var * expf(-(float)(d * d) * inv2l2);
        __syncthreads();
        const float ang0 = 7.66990393942820614859e-4f;   // 2*pi/8192
        const int j = lbk * NTHR + tid;                  // my frequency index
        float fj = sig2 + var;
        for (int d = 1; d <= BF; ++d) {
            int m = (j * d) & (T_PTS - 1);               // exact int phase
            if (m >= T_PTS / 2) m -= T_PTS;
            fj += 2.f * L.wlg[d] * cosf(ang0 * (float)m);
        }
        const float lgj = logf(fj);
        lg[j] = lgj;                                     // publish to ws
        const double ls = blockReduceSum((double)lgj, redd);
        if (tid == 0) atomicAdd(&acc[0], ls);            // circulant term
        __threadfence();                                 // release my lg store
        __syncthreads();
        if (tid == 0) {                                  // sub-barrier, NLOG blocks
            atomicAdd(bar, 1);
            while (__hip_atomic_load(bar, __ATOMIC_ACQUIRE, __HIP_MEMORY_SCOPE_AGENT) < NLOG)
                __builtin_amdgcn_s_sleep(8);
        }
        __syncthreads();
        for (int i = tid; i < T_PTS; i += NTHR) L.lgl[i] = lg[i];   // stage to LDS
        __syncthreads();
        double corr = 0.0;
        for (int t = 0; t < KPERB; ++t) {
            const int k = lbk * KPERB + t + 1;
            double p = 0.0;
            for (int jj = tid; jj < T_PTS; jj += NTHR) {
                int m = (jj * k) & (T_PTS - 1);
                if (m >= T_PTS / 2) m -= T_PTS;
                p += (double)(L.lgl[jj] * __cosf(ang0 * (float)m));
            }
            double ckv = blockReduceSum(p, redd);
            if (tid == 0) {
                ckv *= (1.0 / (double)T_PTS);
                corr += (double)k * ckv * ckv;
            }
        }
        if (tid == 0) atomicAdd(&acc[1], corr);
    }

    // ================= last-block combine =================
    __syncthreads();
    if (tid == 0) {
        __threadfence();
        const int old = atomicAdd(done, 1);
        if (old == NBLK - 1) {
            __threadfence();
            const double l0 = __hip_atomic_load(&acc[0], __ATOMIC_RELAXED, __HIP_MEMORY_SCOPE_AGENT);
            const double l1 = __hip_atomic_load(&acc[1], __ATOMIC_RELAXED, __HIP_MEMORY_SCOPE_AGENT);
            const double qq = __hip_atomic_load(&acc[2], __ATOMIC_RELAXED, __HIP_MEMORY_SCOPE_AGENT);
            out[0] = (float)(-0.5 * qq - 0.5 * (l0 + l1));
        }
    }
}

extern "C" void kernel_launch(void* const* d_in, const int* in_sizes, int n_in,
                              void* d_out, int out_size, void* d_ws, size_t ws_size,
                              hipStream_t stream) {
    const float* y    = (const float*)d_in[0];
    const float* sig2 = (const float*)d_in[1];
    const float* ell  = (const float*)d_in[2];
    const float* var  = (const float*)d_in[3];
    float* out = (float*)d_out;
    unsigned char* ws = (unsigned char*)d_ws;

    hipMemsetAsync(d_ws, 0, 64, stream);   // acc[3] + bar + done only

    void* args[] = { (void*)&y, (void*)&sig2, (void*)&ell, (void*)&var,
                     (void*)&out, (void*)&ws };
    hipLaunchCooperativeKernel((void*)gp_mll_kernel, dim3(NBLK), dim3(NTHR),
                               args, 0, stream);
}